// Round 3
// baseline (254.350 us; speedup 1.0000x reference)
//
#include <hip/hip_runtime.h>

#define B_N 256
#define C_N 50000
#define D_N 512
#define ALPHA 0.5f

typedef float v4f __attribute__((ext_vector_type(4)));

#define ONEHOT4 (B_N * (C_N / 4))   // 3,200,000 float4s of onehot
#define CENT4   (C_N * (D_N / 4))   // 6,400,000 float4s of centers

#define NB     2048                  // total blocks (8/CU, 32 waves/CU @256thr)
#define OH_NB  224                   // scan blocks:  51.2MB read  -> 229 KB/blk
#define CP_NB  (NB - OH_NB)          // 1824 copy blocks: 409.6MB r+w -> 225 KB/blk

// Dispatch 1: block-phase-unswitched label-scan + centers->new_centers copy.
// Plain (cacheable) loads/stores: the bench replays this graph back-to-back,
// so onehot/centers re-reads can hit the 256MB Infinity Cache; `nt` variants
// (rounds 1-2) forfeited that and ran ~4.3 TB/s vs the ~6.3 TB/s ceiling.
// Labels: each one-hot row has exactly one 1.0, so exactly one lane writes
// labels[b] -- no atomics, no counts, no memset.
__global__ __launch_bounds__(256) void scan_copy(
        const float* __restrict__ onehot,
        const v4f* __restrict__ centers4,
        v4f* __restrict__ newc4,
        int* __restrict__ labels) {
    const int t = threadIdx.x;
    if (blockIdx.x < OH_NB) {
        const v4f* oh4 = (const v4f*)onehot;
        const int stride = OH_NB * 256;
        int i = blockIdx.x * 256 + t;
        for (; i + stride < ONEHOT4; i += 2 * stride) {
            v4f a = oh4[i];
            v4f b = oh4[i + stride];
            if (a[0] != 0.f || a[1] != 0.f || a[2] != 0.f || a[3] != 0.f) {
                int base = i * 4;
#pragma unroll
                for (int k = 0; k < 4; ++k)
                    if (a[k] != 0.f) {
                        int g = base + k, r = g / C_N;
                        labels[r] = g - r * C_N;
                    }
            }
            if (b[0] != 0.f || b[1] != 0.f || b[2] != 0.f || b[3] != 0.f) {
                int base = (i + stride) * 4;
#pragma unroll
                for (int k = 0; k < 4; ++k)
                    if (b[k] != 0.f) {
                        int g = base + k, r = g / C_N;
                        labels[r] = g - r * C_N;
                    }
            }
        }
        if (i < ONEHOT4) {
            v4f a = oh4[i];
            if (a[0] != 0.f || a[1] != 0.f || a[2] != 0.f || a[3] != 0.f) {
                int base = i * 4;
#pragma unroll
                for (int k = 0; k < 4; ++k)
                    if (a[k] != 0.f) {
                        int g = base + k, r = g / C_N;
                        labels[r] = g - r * C_N;
                    }
            }
        }
    } else {
        // untouched rows (>=49744 of 50000) are final; touched rows get
        // overwritten by the fixup half of `finish` afterwards.
        const int stride = CP_NB * 256;
        int j = (blockIdx.x - OH_NB) * 256 + t;
        for (; j + stride < CENT4; j += 2 * stride) {
            v4f a = centers4[j];
            v4f b = centers4[j + stride];
            newc4[j] = a;
            newc4[j + stride] = b;
        }
        if (j < CENT4)
            newc4[j] = centers4[j];
    }
}

// Dispatch 2: blocks 0..255 compute result[b] = ||x_b - centers[label_b]||^2;
// blocks 256..511 rewrite the <=256 touched new_centers rows:
//   new[c] = centers[c]*(1 - a*n/(n+1)) + (a/(n+1)) * sum_{label_b=c} x[b]
// Dedup across duplicate labels via first-occurrence scan of the LDS-resident
// 1 KB label list.
__global__ __launch_bounds__(128) void finish(
        const float* __restrict__ x,
        const float* __restrict__ centers,
        const int* __restrict__ labels,
        float* __restrict__ result,
        float* __restrict__ newc) {
    __shared__ int lab[B_N];
    __shared__ float ws[2];
    int t = threadIdx.x;                         // 0..127, one float4 per thread
    lab[t] = labels[t];
    lab[t + 128] = labels[t + 128];
    __syncthreads();

    if (blockIdx.x < B_N) {
        // ---- squared distance ----
        int b = blockIdx.x;
        int c = lab[b];
        v4f xv = ((const v4f*)(x + (size_t)b * D_N))[t];
        v4f cv = ((const v4f*)(centers + (size_t)c * D_N))[t];
        v4f d = xv - cv;
        float s = d[0] * d[0] + d[1] * d[1] + d[2] * d[2] + d[3] * d[3];
#pragma unroll
        for (int off = 32; off > 0; off >>= 1) s += __shfl_down(s, off, 64);
        if ((t & 63) == 0) ws[t >> 6] = s;
        __syncthreads();
        if (t == 0) result[b] = ws[0] + ws[1];
    } else {
        // ---- touched-row fixup ----
        int b = blockIdx.x - B_N;
        int c = lab[b];
        for (int i = 0; i < b; ++i)
            if (lab[i] == c) return;             // not first occurrence: done
        int n = 0;
        v4f sx = {0.f, 0.f, 0.f, 0.f};
        for (int i = 0; i < B_N; ++i) {
            if (lab[i] == c) {                   // wave-uniform branch
                ++n;
                sx += ((const v4f*)(x + (size_t)i * D_N))[t];
            }
        }
        float inv = 1.0f / (float)(n + 1);
        float ac = 1.0f - ALPHA * (float)n * inv;
        float bc = ALPHA * inv;
        v4f cv = ((const v4f*)(centers + (size_t)c * D_N))[t];
        v4f res = cv * ac + sx * bc;
        ((v4f*)(newc + (size_t)c * D_N))[t] = res;
    }
}

extern "C" void kernel_launch(void* const* d_in, const int* in_sizes, int n_in,
                              void* d_out, int out_size, void* d_ws, size_t ws_size,
                              hipStream_t stream) {
    const float* x       = (const float*)d_in[0];   // [B, D]
    const float* onehot  = (const float*)d_in[1];   // [B, C]
    const float* centers = (const float*)d_in[2];   // [C, D]
    float* out    = (float*)d_out;
    float* result = out;                            // [B, 1] -> 256 floats
    float* newc   = out + B_N;                      // [C, D], 16B-aligned (1 KB offset)

    int* labels = (int*)d_ws;                       // B ints (1 KB of workspace)

    scan_copy<<<NB, 256, 0, stream>>>(onehot, (const v4f*)centers,
                                      (v4f*)newc, labels);
    finish<<<512, 128, 0, stream>>>(x, centers, labels, result, newc);
}

// Round 4
// 240.217 us; speedup vs baseline: 1.0588x; 1.0588x over previous
//
#include <hip/hip_runtime.h>

#define B_N 256
#define C_N 50000
#define D_N 512
#define ALPHA 0.5f

typedef float v4f __attribute__((ext_vector_type(4)));

#define ONEHOT4 (B_N * (C_N / 4))   // 3,200,000 float4s of onehot
#define CENT4   (C_N * (D_N / 4))   // 6,400,000 float4s of centers

#define NB     2048                  // total blocks (8/CU, 32 waves/CU @256thr)
#define OH_NB  416                   // scan blocks (round-2 proven split)
#define CP_NB  (NB - OH_NB)          // 1632 copy blocks

// Rare-path helper: decode the one-hot hit(s) in a row-chunk into labels[].
__device__ __forceinline__ void check_row(v4f v, int i, int* __restrict__ labels) {
    if (v[0] != 0.f || v[1] != 0.f || v[2] != 0.f || v[3] != 0.f) {
        int base = i * 4;
#pragma unroll
        for (int k = 0; k < 4; ++k)
            if (v[k] != 0.f) {
                int g = base + k, r = g / C_N;
                labels[r] = g - r * C_N;         // exactly one writer per row
            }
    }
}

// Dispatch 1: block-phase-unswitched label-scan + centers->new_centers copy.
// nt loads/stores (round-2 measured-best; plain stores regressed to 2.2 TB/s
// via the L2 write-allocate path -- round-3 counters). 4x unroll: 4
// independent nontemporal dwordx4 ops in flight per thread for MLP.
__global__ __launch_bounds__(256) void scan_copy(
        const float* __restrict__ onehot,
        const v4f* __restrict__ centers4,
        v4f* __restrict__ newc4,
        int* __restrict__ labels) {
    const int t = threadIdx.x;
    if (blockIdx.x < OH_NB) {
        const v4f* oh4 = (const v4f*)onehot;
        const int S = OH_NB * 256;
        int i = blockIdx.x * 256 + t;
        for (; i + 3 * S < ONEHOT4; i += 4 * S) {
            v4f a0 = __builtin_nontemporal_load(oh4 + i);
            v4f a1 = __builtin_nontemporal_load(oh4 + i + S);
            v4f a2 = __builtin_nontemporal_load(oh4 + i + 2 * S);
            v4f a3 = __builtin_nontemporal_load(oh4 + i + 3 * S);
            check_row(a0, i, labels);
            check_row(a1, i + S, labels);
            check_row(a2, i + 2 * S, labels);
            check_row(a3, i + 3 * S, labels);
        }
        for (; i < ONEHOT4; i += S)
            check_row(__builtin_nontemporal_load(oh4 + i), i, labels);
    } else {
        // untouched rows (>=49744 of 50000) are final; touched rows get
        // overwritten by the fixup half of `finish` afterwards.
        const int S = CP_NB * 256;
        int j = (blockIdx.x - OH_NB) * 256 + t;
        for (; j + 3 * S < CENT4; j += 4 * S) {
            v4f a0 = __builtin_nontemporal_load(centers4 + j);
            v4f a1 = __builtin_nontemporal_load(centers4 + j + S);
            v4f a2 = __builtin_nontemporal_load(centers4 + j + 2 * S);
            v4f a3 = __builtin_nontemporal_load(centers4 + j + 3 * S);
            __builtin_nontemporal_store(a0, newc4 + j);
            __builtin_nontemporal_store(a1, newc4 + j + S);
            __builtin_nontemporal_store(a2, newc4 + j + 2 * S);
            __builtin_nontemporal_store(a3, newc4 + j + 3 * S);
        }
        for (; j < CENT4; j += S)
            __builtin_nontemporal_store(__builtin_nontemporal_load(centers4 + j),
                                        newc4 + j);
    }
}

// Dispatch 2: blocks 0..255 compute result[b] = ||x_b - centers[label_b]||^2;
// blocks 256..511 rewrite the <=256 touched new_centers rows:
//   new[c] = centers[c]*(1 - a*n/(n+1)) + (a/(n+1)) * sum_{label_b=c} x[b]
// Dedup across duplicate labels via first-occurrence scan of the LDS-resident
// 1 KB label list.
__global__ __launch_bounds__(128) void finish(
        const float* __restrict__ x,
        const float* __restrict__ centers,
        const int* __restrict__ labels,
        float* __restrict__ result,
        float* __restrict__ newc) {
    __shared__ int lab[B_N];
    __shared__ float ws[2];
    int t = threadIdx.x;                         // 0..127, one float4 per thread
    lab[t] = labels[t];
    lab[t + 128] = labels[t + 128];
    __syncthreads();

    if (blockIdx.x < B_N) {
        // ---- squared distance ----
        int b = blockIdx.x;
        int c = lab[b];
        v4f xv = ((const v4f*)(x + (size_t)b * D_N))[t];
        v4f cv = ((const v4f*)(centers + (size_t)c * D_N))[t];
        v4f d = xv - cv;
        float s = d[0] * d[0] + d[1] * d[1] + d[2] * d[2] + d[3] * d[3];
#pragma unroll
        for (int off = 32; off > 0; off >>= 1) s += __shfl_down(s, off, 64);
        if ((t & 63) == 0) ws[t >> 6] = s;
        __syncthreads();
        if (t == 0) result[b] = ws[0] + ws[1];
    } else {
        // ---- touched-row fixup ----
        int b = blockIdx.x - B_N;
        int c = lab[b];
        for (int i = 0; i < b; ++i)
            if (lab[i] == c) return;             // not first occurrence: done
        int n = 0;
        v4f sx = {0.f, 0.f, 0.f, 0.f};
        for (int i = 0; i < B_N; ++i) {
            if (lab[i] == c) {                   // wave-uniform branch
                ++n;
                sx += ((const v4f*)(x + (size_t)i * D_N))[t];
            }
        }
        float inv = 1.0f / (float)(n + 1);
        float ac = 1.0f - ALPHA * (float)n * inv;
        float bc = ALPHA * inv;
        v4f cv = ((const v4f*)(centers + (size_t)c * D_N))[t];
        v4f res = cv * ac + sx * bc;
        ((v4f*)(newc + (size_t)c * D_N))[t] = res;
    }
}

extern "C" void kernel_launch(void* const* d_in, const int* in_sizes, int n_in,
                              void* d_out, int out_size, void* d_ws, size_t ws_size,
                              hipStream_t stream) {
    const float* x       = (const float*)d_in[0];   // [B, D]
    const float* onehot  = (const float*)d_in[1];   // [B, C]
    const float* centers = (const float*)d_in[2];   // [C, D]
    float* out    = (float*)d_out;
    float* result = out;                            // [B, 1] -> 256 floats
    float* newc   = out + B_N;                      // [C, D], 16B-aligned (1 KB offset)

    int* labels = (int*)d_ws;                       // B ints (1 KB of workspace)

    scan_copy<<<NB, 256, 0, stream>>>(onehot, (const v4f*)centers,
                                      (v4f*)newc, labels);
    finish<<<512, 128, 0, stream>>>(x, centers, labels, result, newc);
}